// Round 12
// baseline (505.110 us; speedup 1.0000x reference)
//
#include <hip/hip_runtime.h>
#include <hip/hip_fp16.h>
#include <stdint.h>

typedef int i32x4 __attribute__((ext_vector_type(4)));

#define IN_F  4096
#define OUT_F 11008
#define MROWS 8192
#define BM 256
#define BN 256
#define BKB 64                     // K-bytes per tile (i8) -> one 16x16x64 K-depth
#define NKT (IN_F / BKB)           // 64
#define GRID_M (MROWS / BM)        // 32
#define GRID_N (OUT_F / BN)        // 43
#define NBLK (GRID_M * GRID_N)     // 1376 (divisible by 8 -> bijective XCD swizzle)

#define AS1 __attribute__((address_space(1)))
#define AS3 __attribute__((address_space(3)))

// ---------------- Pre-pass 1: smooth + fake-quant activations to int8 ----------------
__global__ __launch_bounds__(256) void quant_act_kernel(
    const float* __restrict__ x, const float* __restrict__ pqs,
    const float* __restrict__ iscale, int8_t* __restrict__ q)
{
    const int i = blockIdx.x * blockDim.x + threadIdx.x;
    const float s = iscale[0];
    const size_t base = (size_t)i * 8;
    const int col = (int)(base & (IN_F - 1));

    const float4 x0 = *(const float4*)(x + base);
    const float4 x1 = *(const float4*)(x + base + 4);
    const float4 p0 = *(const float4*)(pqs + col);
    const float4 p1 = *(const float4*)(pqs + col + 4);

    float xs[8];
    xs[0] = x0.x * p0.x; xs[1] = x0.y * p0.y; xs[2] = x0.z * p0.z; xs[3] = x0.w * p0.w;
    xs[4] = x1.x * p1.x; xs[5] = x1.y * p1.y; xs[6] = x1.z * p1.z; xs[7] = x1.w * p1.w;

    unsigned int lo = 0, hi = 0;
    #pragma unroll
    for (int j = 0; j < 8; ++j) {
        float xm = __half2float(__float2half(xs[j]));   // fp16 Mul materialization
        float qf = nearbyintf(xm / s);                  // f32 div + RNE
        qf = fminf(fmaxf(qf, -128.0f), 127.0f);
        unsigned int b = (unsigned int)((int)qf & 0xff);
        if (j < 4) lo |= b << (8 * j);
        else       hi |= b << (8 * (j - 4));
    }
    *(uint2*)(q + base) = make_uint2(lo, hi);
}

// ---------------- Pre-pass 2: pack int32-stored int8 weights ----------------
__global__ __launch_bounds__(256) void pack_w_kernel(
    const int* __restrict__ w, int8_t* __restrict__ wq)
{
    const size_t i = (size_t)(blockIdx.x * blockDim.x + threadIdx.x) * 8;
    const int4 a = *(const int4*)(w + i);
    const int4 b = *(const int4*)(w + i + 4);
    unsigned int lo = (a.x & 0xff) | ((a.y & 0xff) << 8) | ((a.z & 0xff) << 16) | ((unsigned int)(a.w & 0xff) << 24);
    unsigned int hi = (b.x & 0xff) | ((b.y & 0xff) << 8) | ((b.z & 0xff) << 16) | ((unsigned int)(b.w & 0xff) << 24);
    *(uint2*)(wq + i) = make_uint2(lo, hi);
}

// ---------------- 256x256 i8 GEMM, triple-buffer BK=64, m201-style phase split ----------------
// 8 waves (2M x 4N), per-wave 128x64 output = 8x4 16x16 frags, 32 MFMA / K-tile.
// LDS: 3 bufs x (A 16KB + B 16KB) = 96 KiB. Staging 2 K-tiles ahead -> vmcnt(4).
// Each K-tile = 2 phases; reads and MFMAs live in SEPARATE barrier intervals:
// {reads issue + stage | bar | lgkmcnt(0)+sched_barrier | prio1 | 16 MFMA | prio0 | bar}
// so setprio never starves a sibling wave's ds_read issue (convoy fix).
__global__ __launch_bounds__(512, 2) void gemm_i8_256_kernel(
    const int8_t* __restrict__ Aq,     // [8192][4096]
    const int8_t* __restrict__ Wq,     // [11008][4096]
    const float* __restrict__ wscale,  // [11008]
    const float* __restrict__ iscale,  // [1]
    float* __restrict__ out)           // [8192][11008] f32
{
    __shared__ int8_t lds[98304];      // 3 x 32768 (A 16K | B 16K)

    const int tid  = threadIdx.x;
    const int lane = tid & 63;
    const int wv   = tid >> 6;         // 0..7
    const int wr   = wv >> 2;          // 0..1  (M half)
    const int wc   = wv & 3;           // 0..3  (N quarter)

    // T1: XCD-aware swizzle
    const int bid = (int)blockIdx.x;
    const int swz = (bid & 7) * (NBLK / 8) + (bid >> 3);
    const int bm = swz / GRID_N;
    const int bn = swz % GRID_N;
    const int brow = bm * BM, bcol = bn * BN;

    const int8_t* Ab = Aq + (size_t)brow * IN_F;
    const int8_t* Bb = Wq + (size_t)bcol * IN_F;

    // staging: 1024 16B-chunks per operand tile; 2 A + 2 B chunks per thread
    int srow[2], scol[2], sdst[2];
    #pragma unroll
    for (int i = 0; i < 2; ++i) {
        const int n = i * 512 + tid;                      // 0..1023
        srow[i] = n >> 2;                                 // tile row (0..255)
        scol[i] = ((n & 3) ^ ((srow[i] >> 1) & 3)) * 16;  // inverse-swizzled source chunk
        sdst[i] = n * 16;                                 // linear LDS dest
    }

    #define STAGE_A(t) do { AS3 int8_t* Ad = (AS3 int8_t*)(lds + ((t) % 3) * 32768); \
        const int k0_ = (t) * BKB; \
        _Pragma("unroll") for (int i_ = 0; i_ < 2; ++i_) \
            __builtin_amdgcn_global_load_lds((const AS1 void*)(Ab + (size_t)srow[i_] * IN_F + k0_ + scol[i_]), \
                                             (AS3 void*)(Ad + sdst[i_]), 16, 0, 0); } while (0)
    #define STAGE_B(t) do { AS3 int8_t* Bd = (AS3 int8_t*)(lds + ((t) % 3) * 32768 + 16384); \
        const int k0_ = (t) * BKB; \
        _Pragma("unroll") for (int i_ = 0; i_ < 2; ++i_) \
            __builtin_amdgcn_global_load_lds((const AS1 void*)(Bb + (size_t)srow[i_] * IN_F + k0_ + scol[i_]), \
                                             (AS3 void*)(Bd + sdst[i_]), 16, 0, 0); } while (0)

    i32x4 acc[8][4] = {};

    const int rl = lane & 15;
    const int hk = lane >> 4;                          // K-quarter 0..3
    const int koff = ((hk ^ ((rl >> 1) & 3)) * 16);    // bank-exact swizzled chunk
    const int a_base = (wr * 128 + rl) * 64;           // + mf*1024 + koff
    const int b_base = (wc * 64 + rl) * 64;            // + nf*1024 + koff

    // prologue: stage tiles 0 and 1 (8 loads in flight)
    STAGE_A(0); STAGE_B(0);
    STAGE_A(1); STAGE_B(1);

    for (int kt = 0; kt < NKT; ++kt) {
        if (kt + 1 < NKT) asm volatile("s_waitcnt vmcnt(4)" ::: "memory");  // T4: counted
        else              asm volatile("s_waitcnt vmcnt(0)" ::: "memory");
        __builtin_amdgcn_s_barrier();              // B1: tile kt staged everywhere
        __builtin_amdgcn_sched_barrier(0);

        const int8_t* At = lds + (kt % 3) * 32768;
        const int8_t* Bt = At + 16384;

        // ---- R0: issue reads for quadrant 0 (A-half0 + all B); issue stage A(kt+2) ----
        i32x4 a0[4], b[4], a1[4];
        #pragma unroll
        for (int mf = 0; mf < 4; ++mf)
            a0[mf] = *(const i32x4*)(At + a_base + mf * 1024 + koff);
        #pragma unroll
        for (int nf = 0; nf < 4; ++nf)
            b[nf] = *(const i32x4*)(Bt + b_base + nf * 1024 + koff);
        if (kt + 2 < NKT) STAGE_A(kt + 2);
        __builtin_amdgcn_s_barrier();              // reads issued by all waves
        asm volatile("s_waitcnt lgkmcnt(0)" ::: "memory");
        __builtin_amdgcn_sched_barrier(0);         // rule #18: pin MFMAs below the wait
        // ---- M0: MFMA-only interval ----
        __builtin_amdgcn_s_setprio(1);             // T5: safe here, no reads to starve
        #pragma unroll
        for (int mf = 0; mf < 4; ++mf)
            #pragma unroll
            for (int nf = 0; nf < 4; ++nf)
                acc[mf][nf] = __builtin_amdgcn_mfma_i32_16x16x64_i8(a0[mf], b[nf], acc[mf][nf], 0, 0, 0);
        __builtin_amdgcn_s_setprio(0);
        __builtin_amdgcn_sched_barrier(0);
        __builtin_amdgcn_s_barrier();              // end M0

        // ---- R1: issue reads for quadrant 1 (A-half1); issue stage B(kt+2) ----
        #pragma unroll
        for (int mf = 0; mf < 4; ++mf)
            a1[mf] = *(const i32x4*)(At + a_base + (mf + 4) * 1024 + koff);
        if (kt + 2 < NKT) STAGE_B(kt + 2);
        __builtin_amdgcn_s_barrier();              // reads issued by all waves
        asm volatile("s_waitcnt lgkmcnt(0)" ::: "memory");
        __builtin_amdgcn_sched_barrier(0);
        // ---- M1: MFMA-only interval ----
        __builtin_amdgcn_s_setprio(1);
        #pragma unroll
        for (int mf = 0; mf < 4; ++mf)
            #pragma unroll
            for (int nf = 0; nf < 4; ++nf)
                acc[mf + 4][nf] = __builtin_amdgcn_mfma_i32_16x16x64_i8(a1[mf], b[nf], acc[mf + 4][nf], 0, 0, 0);
        __builtin_amdgcn_s_setprio(0);
        __builtin_amdgcn_sched_barrier(0);
        // trailing barrier merges with next iteration's B1
    }

    // epilogue: out = f32(acc * s * ws[col]); C/D map: col=lane&15, row=hk*4+j
    const float s = iscale[0];
    #pragma unroll
    for (int nf = 0; nf < 4; ++nf) {
        const int col = bcol + wc * 64 + nf * 16 + rl;
        const float sc = s * wscale[col];
        #pragma unroll
        for (int mf = 0; mf < 8; ++mf) {
            const int r0 = brow + wr * 128 + mf * 16 + hk * 4;
            #pragma unroll
            for (int j = 0; j < 4; ++j)
                out[(size_t)(r0 + j) * OUT_F + col] = (float)acc[mf][nf][j] * sc;
        }
    }
    #undef STAGE_A
    #undef STAGE_B
}

// ---------------- Scalar fallback (no workspace), pathological ws only ----------------
__global__ __launch_bounds__(256) void simple_ref_kernel(
    const float* __restrict__ x, const int* __restrict__ w,
    const float* __restrict__ wsc, const float* __restrict__ isc,
    const float* __restrict__ pqs, float* __restrict__ out)
{
    const float s = isc[0];
    const int m = blockIdx.x;
    const int o = blockIdx.y * 256 + threadIdx.x;
    if (o >= OUT_F) return;
    const float wso = wsc[o];
    const float* xr = x + (size_t)m * IN_F;
    const int* wr = w + (size_t)o * IN_F;
    float acc = 0.0f;
    for (int k = 0; k < IN_F; ++k) {
        float xm = __half2float(__float2half(xr[k] * pqs[k]));
        float qf = nearbyintf(xm / s);
        qf = fminf(fmaxf(qf, -128.0f), 127.0f);
        float xdq = __half2float(__float2half(qf * s));
        float wdq = __half2float(__float2half((float)wr[k] * wso));
        acc = fmaf(xdq, wdq, acc);
    }
    out[(size_t)m * OUT_F + o] = acc;
}

extern "C" void kernel_launch(void* const* d_in, const int* in_sizes, int n_in,
                              void* d_out, int out_size, void* d_ws, size_t ws_size,
                              hipStream_t stream)
{
    const float* x   = nullptr;
    const int*   w   = nullptr;
    const float* wsc = nullptr;
    const float* isc = nullptr;
    const float* pqs = nullptr;
    for (int i = 0; i < n_in; ++i) {
        switch (in_sizes[i]) {
            case MROWS * IN_F:   x   = (const float*)d_in[i]; break; // 33554432
            case OUT_F * IN_F:   w   = (const int*)d_in[i];   break; // 45088768
            case OUT_F:          wsc = (const float*)d_in[i]; break; // 11008
            case 1:              isc = (const float*)d_in[i]; break;
            case IN_F:           pqs = (const float*)d_in[i]; break; // 4096
        }
    }
    float* out = (float*)d_out;   // fp16 reference output -> float32 buffer

    const size_t need = (size_t)MROWS * IN_F + (size_t)OUT_F * IN_F;  // 78.6 MB
    if (d_ws == nullptr || ws_size < need) {
        dim3 grid(MROWS, (OUT_F + 255) / 256);
        simple_ref_kernel<<<grid, 256, 0, stream>>>(x, w, wsc, isc, pqs, out);
        return;
    }

    int8_t* Aq = (int8_t*)d_ws;
    int8_t* Wq = Aq + (size_t)MROWS * IN_F;

    quant_act_kernel<<<(MROWS * IN_F / 8) / 256, 256, 0, stream>>>(x, pqs, isc, Aq);
    pack_w_kernel<<<(OUT_F * IN_F / 8) / 256, 256, 0, stream>>>(w, Wq);
    gemm_i8_256_kernel<<<NBLK, 512, 0, stream>>>(Aq, Wq, wsc, isc, out);
}

// Round 13
// 484.165 us; speedup vs baseline: 1.0433x; 1.0433x over previous
//
#include <hip/hip_runtime.h>
#include <hip/hip_fp16.h>
#include <stdint.h>

typedef int i32x4 __attribute__((ext_vector_type(4)));

#define IN_F  4096
#define OUT_F 11008
#define MROWS 8192
#define BM 256
#define BN 256
#define BKB 64                     // K-bytes per tile (i8) -> one 16x16x64 K-depth
#define NKT (IN_F / BKB)           // 64
#define GRID_M (MROWS / BM)        // 32
#define GRID_N (OUT_F / BN)        // 43
#define NBLK (GRID_M * GRID_N)     // 1376 (divisible by 8 -> bijective XCD swizzle)

#define AS1 __attribute__((address_space(1)))
#define AS3 __attribute__((address_space(3)))

// ---------------- Pre-pass 1: smooth + fake-quant activations to int8 ----------------
__global__ __launch_bounds__(256) void quant_act_kernel(
    const float* __restrict__ x, const float* __restrict__ pqs,
    const float* __restrict__ iscale, int8_t* __restrict__ q)
{
    const int i = blockIdx.x * blockDim.x + threadIdx.x;
    const float s = iscale[0];
    const size_t base = (size_t)i * 8;
    const int col = (int)(base & (IN_F - 1));

    const float4 x0 = *(const float4*)(x + base);
    const float4 x1 = *(const float4*)(x + base + 4);
    const float4 p0 = *(const float4*)(pqs + col);
    const float4 p1 = *(const float4*)(pqs + col + 4);

    float xs[8];
    xs[0] = x0.x * p0.x; xs[1] = x0.y * p0.y; xs[2] = x0.z * p0.z; xs[3] = x0.w * p0.w;
    xs[4] = x1.x * p1.x; xs[5] = x1.y * p1.y; xs[6] = x1.z * p1.z; xs[7] = x1.w * p1.w;

    unsigned int lo = 0, hi = 0;
    #pragma unroll
    for (int j = 0; j < 8; ++j) {
        float xm = __half2float(__float2half(xs[j]));   // fp16 Mul materialization
        float qf = nearbyintf(xm / s);                  // f32 div + RNE
        qf = fminf(fmaxf(qf, -128.0f), 127.0f);
        unsigned int b = (unsigned int)((int)qf & 0xff);
        if (j < 4) lo |= b << (8 * j);
        else       hi |= b << (8 * (j - 4));
    }
    *(uint2*)(q + base) = make_uint2(lo, hi);
}

// ---------------- Pre-pass 2: pack int32-stored int8 weights ----------------
__global__ __launch_bounds__(256) void pack_w_kernel(
    const int* __restrict__ w, int8_t* __restrict__ wq)
{
    const size_t i = (size_t)(blockIdx.x * blockDim.x + threadIdx.x) * 8;
    const int4 a = *(const int4*)(w + i);
    const int4 b = *(const int4*)(w + i + 4);
    unsigned int lo = (a.x & 0xff) | ((a.y & 0xff) << 8) | ((a.z & 0xff) << 16) | ((unsigned int)(a.w & 0xff) << 24);
    unsigned int hi = (b.x & 0xff) | ((b.y & 0xff) << 8) | ((b.z & 0xff) << 16) | ((unsigned int)(b.w & 0xff) << 24);
    *(uint2*)(wq + i) = make_uint2(lo, hi);
}

// ---------------- 256x256 i8 GEMM, 16 waves (4x4 of 64x64), 4 waves/SIMD ----------------
// acc[4][4] = 64 AGPR, total ~120 regs/wave -> 4 waves/SIMD (TLP overlap of
// LDS pipe and MFMA pipe across waves -- the convoy fix rounds 10-12 couldn't
// get from scheduling at 2 waves/SIMD).
// LDS: 3 bufs x (A 16KB + B 16KB) = 96 KiB, staging 2 tiles ahead, vmcnt(2).
// ONE barrier per K-tile: all waves pass B1(kt) only after their kt-1 reads
// completed (lgkmcnt before consuming MFMA), so stage(kt+2) never races.
// Swizzle (r11-proven, 0 conflicts): chunk ^= (row>>1)&3, both sides.
__global__ __launch_bounds__(1024, 4) void gemm_i8_256_kernel(
    const int8_t* __restrict__ Aq,     // [8192][4096]
    const int8_t* __restrict__ Wq,     // [11008][4096]
    const float* __restrict__ wscale,  // [11008]
    const float* __restrict__ iscale,  // [1]
    float* __restrict__ out)           // [8192][11008] f32
{
    __shared__ int8_t lds[98304];      // 3 x 32768 (A 16K | B 16K)

    const int tid  = threadIdx.x;
    const int lane = tid & 63;
    const int wv   = tid >> 6;         // 0..15
    const int wr   = wv >> 2;          // 0..3  (M quarter)
    const int wc   = wv & 3;           // 0..3  (N quarter)

    // T1: XCD-aware swizzle
    const int bid = (int)blockIdx.x;
    const int swz = (bid & 7) * (NBLK / 8) + (bid >> 3);
    const int bm = swz / GRID_N;
    const int bn = swz % GRID_N;
    const int brow = bm * BM, bcol = bn * BN;

    const int8_t* Ab = Aq + (size_t)brow * IN_F;
    const int8_t* Bb = Wq + (size_t)bcol * IN_F;

    // staging: 1024 16B-chunks per operand tile; ONE chunk per thread per operand
    const int srow = tid >> 2;                          // tile row (0..255)
    const int scol = ((tid & 3) ^ ((srow >> 1) & 3)) * 16;  // inverse-swizzled source
    const int sdst = tid * 16;                          // linear LDS dest

    #define STAGE_A(t) __builtin_amdgcn_global_load_lds( \
        (const AS1 void*)(Ab + (size_t)srow * IN_F + (t) * BKB + scol), \
        (AS3 void*)(lds + ((t) % 3) * 32768 + sdst), 16, 0, 0)
    #define STAGE_B(t) __builtin_amdgcn_global_load_lds( \
        (const AS1 void*)(Bb + (size_t)srow * IN_F + (t) * BKB + scol), \
        (AS3 void*)(lds + ((t) % 3) * 32768 + 16384 + sdst), 16, 0, 0)

    i32x4 acc[4][4] = {};

    const int rl = lane & 15;
    const int hk = lane >> 4;                          // K-quarter 0..3
    const int koff = (hk ^ ((rl >> 1) & 3)) * 16;      // bank-exact swizzled chunk
    const int a_base = (wr * 64 + rl) * 64;            // + mf*1024 + koff
    const int b_base = (wc * 64 + rl) * 64;            // + nf*1024 + koff

    // prologue: stage tiles 0 and 1 (4 loads in flight per wave)
    STAGE_A(0); STAGE_B(0);
    STAGE_A(1); STAGE_B(1);

    for (int kt = 0; kt < NKT; ++kt) {
        if (kt + 1 < NKT) asm volatile("s_waitcnt vmcnt(2)" ::: "memory");  // T4: counted
        else              asm volatile("s_waitcnt vmcnt(0)" ::: "memory");
        __builtin_amdgcn_s_barrier();              // B1: tile kt staged; kt-1 reads done

        if (kt + 2 < NKT) { STAGE_A(kt + 2); STAGE_B(kt + 2); }

        const int8_t* At = lds + (kt % 3) * 32768;
        const int8_t* Bt = At + 16384;

        i32x4 a[4], b[4];
        #pragma unroll
        for (int mf = 0; mf < 4; ++mf)
            a[mf] = *(const i32x4*)(At + a_base + mf * 1024 + koff);
        #pragma unroll
        for (int nf = 0; nf < 4; ++nf)
            b[nf] = *(const i32x4*)(Bt + b_base + nf * 1024 + koff);
        #pragma unroll
        for (int mf = 0; mf < 4; ++mf)
            #pragma unroll
            for (int nf = 0; nf < 4; ++nf)
                acc[mf][nf] = __builtin_amdgcn_mfma_i32_16x16x64_i8(a[mf], b[nf], acc[mf][nf], 0, 0, 0);
        // no end barrier: next iteration's B1 dominates (reads complete before
        // each wave's consuming MFMAs, which precede its B1 arrival)
    }

    // epilogue: out = f32(acc * s * ws[col]); C/D map: col=lane&15, row=hk*4+j
    const float s = iscale[0];
    #pragma unroll
    for (int nf = 0; nf < 4; ++nf) {
        const int col = bcol + wc * 64 + nf * 16 + rl;
        const float sc = s * wscale[col];
        #pragma unroll
        for (int mf = 0; mf < 4; ++mf) {
            const int r0 = brow + wr * 64 + mf * 16 + hk * 4;
            #pragma unroll
            for (int j = 0; j < 4; ++j)
                out[(size_t)(r0 + j) * OUT_F + col] = (float)acc[mf][nf][j] * sc;
        }
    }
    #undef STAGE_A
    #undef STAGE_B
}

// ---------------- Scalar fallback (no workspace), pathological ws only ----------------
__global__ __launch_bounds__(256) void simple_ref_kernel(
    const float* __restrict__ x, const int* __restrict__ w,
    const float* __restrict__ wsc, const float* __restrict__ isc,
    const float* __restrict__ pqs, float* __restrict__ out)
{
    const float s = isc[0];
    const int m = blockIdx.x;
    const int o = blockIdx.y * 256 + threadIdx.x;
    if (o >= OUT_F) return;
    const float wso = wsc[o];
    const float* xr = x + (size_t)m * IN_F;
    const int* wr = w + (size_t)o * IN_F;
    float acc = 0.0f;
    for (int k = 0; k < IN_F; ++k) {
        float xm = __half2float(__float2half(xr[k] * pqs[k]));
        float qf = nearbyintf(xm / s);
        qf = fminf(fmaxf(qf, -128.0f), 127.0f);
        float xdq = __half2float(__float2half(qf * s));
        float wdq = __half2float(__float2half((float)wr[k] * wso));
        acc = fmaf(xdq, wdq, acc);
    }
    out[(size_t)m * OUT_F + o] = acc;
}

extern "C" void kernel_launch(void* const* d_in, const int* in_sizes, int n_in,
                              void* d_out, int out_size, void* d_ws, size_t ws_size,
                              hipStream_t stream)
{
    const float* x   = nullptr;
    const int*   w   = nullptr;
    const float* wsc = nullptr;
    const float* isc = nullptr;
    const float* pqs = nullptr;
    for (int i = 0; i < n_in; ++i) {
        switch (in_sizes[i]) {
            case MROWS * IN_F:   x   = (const float*)d_in[i]; break; // 33554432
            case OUT_F * IN_F:   w   = (const int*)d_in[i];   break; // 45088768
            case OUT_F:          wsc = (const float*)d_in[i]; break; // 11008
            case 1:              isc = (const float*)d_in[i]; break;
            case IN_F:           pqs = (const float*)d_in[i]; break; // 4096
        }
    }
    float* out = (float*)d_out;   // fp16 reference output -> float32 buffer

    const size_t need = (size_t)MROWS * IN_F + (size_t)OUT_F * IN_F;  // 78.6 MB
    if (d_ws == nullptr || ws_size < need) {
        dim3 grid(MROWS, (OUT_F + 255) / 256);
        simple_ref_kernel<<<grid, 256, 0, stream>>>(x, w, wsc, isc, pqs, out);
        return;
    }

    int8_t* Aq = (int8_t*)d_ws;
    int8_t* Wq = Aq + (size_t)MROWS * IN_F;

    quant_act_kernel<<<(MROWS * IN_F / 8) / 256, 256, 0, stream>>>(x, pqs, isc, Aq);
    pack_w_kernel<<<(OUT_F * IN_F / 8) / 256, 256, 0, stream>>>(w, Wq);
    gemm_i8_256_kernel<<<NBLK, 1024, 0, stream>>>(Aq, Wq, wsc, isc, out);
}

// Round 14
// 469.914 us; speedup vs baseline: 1.0749x; 1.0303x over previous
//
#include <hip/hip_runtime.h>
#include <hip/hip_fp16.h>
#include <stdint.h>

typedef int i32x4 __attribute__((ext_vector_type(4)));

#define IN_F  4096
#define OUT_F 11008
#define MROWS 8192
#define BM 256
#define BN 256
#define BKB 64                     // K-bytes per tile (i8) -> one 16x16x64 K-depth
#define NKT (IN_F / BKB)           // 64
#define GRID_M (MROWS / BM)        // 32
#define GRID_N (OUT_F / BN)        // 43
#define NBLK (GRID_M * GRID_N)     // 1376 (divisible by 8 -> bijective XCD swizzle)

#define AS1 __attribute__((address_space(1)))
#define AS3 __attribute__((address_space(3)))

// ---------------- Pre-pass 1: smooth + fake-quant activations to int8 ----------------
__global__ __launch_bounds__(256) void quant_act_kernel(
    const float* __restrict__ x, const float* __restrict__ pqs,
    const float* __restrict__ iscale, int8_t* __restrict__ q)
{
    const int i = blockIdx.x * blockDim.x + threadIdx.x;
    const float s = iscale[0];
    const size_t base = (size_t)i * 8;
    const int col = (int)(base & (IN_F - 1));

    const float4 x0 = *(const float4*)(x + base);
    const float4 x1 = *(const float4*)(x + base + 4);
    const float4 p0 = *(const float4*)(pqs + col);
    const float4 p1 = *(const float4*)(pqs + col + 4);

    float xs[8];
    xs[0] = x0.x * p0.x; xs[1] = x0.y * p0.y; xs[2] = x0.z * p0.z; xs[3] = x0.w * p0.w;
    xs[4] = x1.x * p1.x; xs[5] = x1.y * p1.y; xs[6] = x1.z * p1.z; xs[7] = x1.w * p1.w;

    unsigned int lo = 0, hi = 0;
    #pragma unroll
    for (int j = 0; j < 8; ++j) {
        float xm = __half2float(__float2half(xs[j]));   // fp16 Mul materialization
        float qf = nearbyintf(xm / s);                  // f32 div + RNE
        qf = fminf(fmaxf(qf, -128.0f), 127.0f);
        unsigned int b = (unsigned int)((int)qf & 0xff);
        if (j < 4) lo |= b << (8 * j);
        else       hi |= b << (8 * (j - 4));
    }
    *(uint2*)(q + base) = make_uint2(lo, hi);
}

// ---------------- Pre-pass 2: pack int32-stored int8 weights ----------------
__global__ __launch_bounds__(256) void pack_w_kernel(
    const int* __restrict__ w, int8_t* __restrict__ wq)
{
    const size_t i = (size_t)(blockIdx.x * blockDim.x + threadIdx.x) * 8;
    const int4 a = *(const int4*)(w + i);
    const int4 b = *(const int4*)(w + i + 4);
    unsigned int lo = (a.x & 0xff) | ((a.y & 0xff) << 8) | ((a.z & 0xff) << 16) | ((unsigned int)(a.w & 0xff) << 24);
    unsigned int hi = (b.x & 0xff) | ((b.y & 0xff) << 8) | ((b.z & 0xff) << 16) | ((unsigned int)(b.w & 0xff) << 24);
    *(uint2*)(wq + i) = make_uint2(lo, hi);
}

// ---------------- 256x256 i8 GEMM, 16 waves, quad-buffer, pipelined frag reads ----------------
// r13 geometry (16 waves of 64x64, 4 waves/SIMD) + intra-wave read pipeline:
// tile kt+1's fragments are ds_read DURING tile kt's MFMA cluster, rotated
// in-place into dying frag regs (a[mf] dead after its MFMA row). The top-of-
// iter lgkmcnt(0) then finds reads complete -> LDS latency hidden under MFMA.
// Quad buffer (4x32KB): at iter kt, buffers hold kt (regs already), kt+1
// (being read), kt+2 (staged), kt+3 (being staged; = buf (kt-1)&3, whose
// readers lgkm-completed before this iter's barrier).
// vmcnt ledger: prologue stages 0,1,2 (6 loads); per-iter vmcnt(2) leaves only
// stage(kt+2) in flight -> tile kt+1 resident (needed for early reads);
// kt >= NKT-2 -> vmcnt(0). Swizzle (0-conflict proven r11): chunk ^= (row>>1)&3.
__global__ __launch_bounds__(1024, 4) void gemm_i8_256_kernel(
    const int8_t* __restrict__ Aq,     // [8192][4096]
    const int8_t* __restrict__ Wq,     // [11008][4096]
    const float* __restrict__ wscale,  // [11008]
    const float* __restrict__ iscale,  // [1]
    float* __restrict__ out)           // [8192][11008] f32
{
    __shared__ int8_t lds[131072];     // 4 x 32768 (A 16K | B 16K)

    const int tid  = threadIdx.x;
    const int lane = tid & 63;
    const int wv   = tid >> 6;         // 0..15
    const int wr   = wv >> 2;          // 0..3  (M quarter)
    const int wc   = wv & 3;           // 0..3  (N quarter)

    // T1: XCD-aware swizzle
    const int bid = (int)blockIdx.x;
    const int swz = (bid & 7) * (NBLK / 8) + (bid >> 3);
    const int bm = swz / GRID_N;
    const int bn = swz % GRID_N;
    const int brow = bm * BM, bcol = bn * BN;

    const int8_t* Ab = Aq + (size_t)brow * IN_F;
    const int8_t* Bb = Wq + (size_t)bcol * IN_F;

    // staging: 1024 16B-chunks per operand tile; ONE chunk per thread per operand
    const int srow = tid >> 2;                              // tile row (0..255)
    const int scol = ((tid & 3) ^ ((srow >> 1) & 3)) * 16;  // inverse-swizzled source
    const int sdst = tid * 16;                              // linear LDS dest

    #define STAGE_A(t) __builtin_amdgcn_global_load_lds( \
        (const AS1 void*)(Ab + (size_t)srow * IN_F + (t) * BKB + scol), \
        (AS3 void*)(lds + ((t) & 3) * 32768 + sdst), 16, 0, 0)
    #define STAGE_B(t) __builtin_amdgcn_global_load_lds( \
        (const AS1 void*)(Bb + (size_t)srow * IN_F + (t) * BKB + scol), \
        (AS3 void*)(lds + ((t) & 3) * 32768 + 16384 + sdst), 16, 0, 0)

    i32x4 acc[4][4] = {};
    i32x4 a[4], b[4];

    const int rl = lane & 15;
    const int hk = lane >> 4;                          // K-quarter 0..3
    const int koff = (hk ^ ((rl >> 1) & 3)) * 16;      // bank-exact swizzled chunk
    const int a_base = (wr * 64 + rl) * 64;            // + mf*1024 + koff
    const int b_base = (wc * 64 + rl) * 64;            // + nf*1024 + koff

    // prologue: stage tiles 0,1,2; wait tile 0; read tile-0 frags
    STAGE_A(0); STAGE_B(0);
    STAGE_A(1); STAGE_B(1);
    STAGE_A(2); STAGE_B(2);
    asm volatile("s_waitcnt vmcnt(4)" ::: "memory");   // tile 0 staged
    __builtin_amdgcn_s_barrier();
    #pragma unroll
    for (int mf = 0; mf < 4; ++mf)
        a[mf] = *(const i32x4*)(lds + a_base + mf * 1024 + koff);
    #pragma unroll
    for (int nf = 0; nf < 4; ++nf)
        b[nf] = *(const i32x4*)(lds + 16384 + b_base + nf * 1024 + koff);

    for (int kt = 0; kt < NKT; ++kt) {
        if (kt + 2 < NKT) asm volatile("s_waitcnt vmcnt(2)" ::: "memory");  // tile kt+1 resident
        else              asm volatile("s_waitcnt vmcnt(0)" ::: "memory");
        __builtin_amdgcn_s_barrier();          // + WAR: all waves' reads(kt-1) done (lgkm'd last iter)

        if (kt + 3 < NKT) { STAGE_A(kt + 3); STAGE_B(kt + 3); }

        asm volatile("s_waitcnt lgkmcnt(0)" ::: "memory");  // frag reads of kt (issued last iter) done
        __builtin_amdgcn_sched_barrier(0);     // rule #18: pin MFMAs below the wait

        const int8_t* An = lds + ((kt + 1) & 3) * 32768;    // next-tile bases
        const int8_t* Bn = An + 16384;
        const bool more = (kt + 1 < NKT);

        #pragma unroll
        for (int mf = 0; mf < 4; ++mf) {
            #pragma unroll
            for (int nf = 0; nf < 4; ++nf)
                acc[mf][nf] = __builtin_amdgcn_mfma_i32_16x16x64_i8(a[mf], b[nf], acc[mf][nf], 0, 0, 0);
            if (more)  // a[mf] dead after its row: rotate in next tile's frag (hides under rows mf+1..)
                a[mf] = *(const i32x4*)(An + a_base + mf * 1024 + koff);
        }
        if (more) {
            #pragma unroll
            for (int nf = 0; nf < 4; ++nf)     // b dead after cluster; reads drain under next barrier
                b[nf] = *(const i32x4*)(Bn + b_base + nf * 1024 + koff);
        }
        __builtin_amdgcn_sched_barrier(0);
    }

    // epilogue: out = f32(acc * s * ws[col]); C/D map: col=lane&15, row=hk*4+j
    const float s = iscale[0];
    #pragma unroll
    for (int nf = 0; nf < 4; ++nf) {
        const int col = bcol + wc * 64 + nf * 16 + rl;
        const float sc = s * wscale[col];
        #pragma unroll
        for (int mf = 0; mf < 4; ++mf) {
            const int r0 = brow + wr * 64 + mf * 16 + hk * 4;
            #pragma unroll
            for (int j = 0; j < 4; ++j)
                out[(size_t)(r0 + j) * OUT_F + col] = (float)acc[mf][nf][j] * sc;
        }
    }
    #undef STAGE_A
    #undef STAGE_B
}

// ---------------- Scalar fallback (no workspace), pathological ws only ----------------
__global__ __launch_bounds__(256) void simple_ref_kernel(
    const float* __restrict__ x, const int* __restrict__ w,
    const float* __restrict__ wsc, const float* __restrict__ isc,
    const float* __restrict__ pqs, float* __restrict__ out)
{
    const float s = isc[0];
    const int m = blockIdx.x;
    const int o = blockIdx.y * 256 + threadIdx.x;
    if (o >= OUT_F) return;
    const float wso = wsc[o];
    const float* xr = x + (size_t)m * IN_F;
    const int* wr = w + (size_t)o * IN_F;
    float acc = 0.0f;
    for (int k = 0; k < IN_F; ++k) {
        float xm = __half2float(__float2half(xr[k] * pqs[k]));
        float qf = nearbyintf(xm / s);
        qf = fminf(fmaxf(qf, -128.0f), 127.0f);
        float xdq = __half2float(__float2half(qf * s));
        float wdq = __half2float(__float2half((float)wr[k] * wso));
        acc = fmaf(xdq, wdq, acc);
    }
    out[(size_t)m * OUT_F + o] = acc;
}

extern "C" void kernel_launch(void* const* d_in, const int* in_sizes, int n_in,
                              void* d_out, int out_size, void* d_ws, size_t ws_size,
                              hipStream_t stream)
{
    const float* x   = nullptr;
    const int*   w   = nullptr;
    const float* wsc = nullptr;
    const float* isc = nullptr;
    const float* pqs = nullptr;
    for (int i = 0; i < n_in; ++i) {
        switch (in_sizes[i]) {
            case MROWS * IN_F:   x   = (const float*)d_in[i]; break; // 33554432
            case OUT_F * IN_F:   w   = (const int*)d_in[i];   break; // 45088768
            case OUT_F:          wsc = (const float*)d_in[i]; break; // 11008
            case 1:              isc = (const float*)d_in[i]; break;
            case IN_F:           pqs = (const float*)d_in[i]; break; // 4096
        }
    }
    float* out = (float*)d_out;   // fp16 reference output -> float32 buffer

    const size_t need = (size_t)MROWS * IN_F + (size_t)OUT_F * IN_F;  // 78.6 MB
    if (d_ws == nullptr || ws_size < need) {
        dim3 grid(MROWS, (OUT_F + 255) / 256);
        simple_ref_kernel<<<grid, 256, 0, stream>>>(x, w, wsc, isc, pqs, out);
        return;
    }

    int8_t* Aq = (int8_t*)d_ws;
    int8_t* Wq = Aq + (size_t)MROWS * IN_F;

    quant_act_kernel<<<(MROWS * IN_F / 8) / 256, 256, 0, stream>>>(x, pqs, isc, Aq);
    pack_w_kernel<<<(OUT_F * IN_F / 8) / 256, 256, 0, stream>>>(w, Wq);
    gemm_i8_256_kernel<<<NBLK, 1024, 0, stream>>>(Aq, Wq, wsc, isc, out);
}